// Round 11
// baseline (233.391 us; speedup 1.0000x reference)
//
#include <hip/hip_runtime.h>

#define W 320
#define H 96
#define FS 96
#define BS 8
#define NPLANES 9
#define NCG 4              // channel groups (split-K over channels)
#define CPG 24             // channels per group == R7's per-wave channel count
#define NTHREADS 256       // 4 waves per block; wave = one y row, fully independent
#define CHUNK (BS * NPLANES * H * W)   // 2,211,840 floats per partial plane-set

// 4-byte-aligned float4: x0 = 5*lane is only dword-aligned
typedef float f4 __attribute__((ext_vector_type(4), aligned(4)));
typedef float f4a __attribute__((ext_vector_type(4), aligned(16)));

// ---------------- kernel A: independent per-wave partials ----------------
// Per-wave workload is byte-identical to round-7 (24 channels, one row,
// VX=5, same loads/masks/FMAs). Removed: ALL LDS, ALL barriers, the
// end-of-block reduction. Each wave owns output slice (cg,b,y) exclusively.
__global__ __launch_bounds__(NTHREADS)
void cost_volume_partial(const float* __restrict__ f1,
                         const float* __restrict__ f2,
                         float* __restrict__ ws)
{
    const int t    = threadIdx.x;
    const int wv   = t >> 6;          // wave 0..3 -> row within y4 span
    const int l    = t & 63;
    const int bx   = blockIdx.x;
    const int cg   = bx & 3;          // channel group 0..3
    const int rest = bx >> 2;
    const int y4   = rest % 24;
    const int b    = rest / 24;
    const int y    = y4 * 4 + wv;

    const int x0 = 5 * l;
    const int o0 = (x0 - 4 < 0)   ? 0   : x0 - 4;   // quad: e0..e3
    const int o2 = (x0 + 4 > 316) ? 316 : x0 + 4;   // quad: e8..e11
    const int o3 = (x0 + 8 > 319) ? 319 : x0 + 8;   // scalar: e12
    const unsigned mlo = (l == 0)  ? 0u : ~0u;
    const unsigned mhi = (l == 63) ? 0u : ~0u;
    const bool hi = (l == 63);                      // e8 (col 319) = q2.w

    const size_t rowoff = ((size_t)(b * FS) * H + y) * W;
    const float* f1w = f1 + rowoff + (size_t)(cg * CPG) * (H * W);
    const float* f2w = f2 + rowoff + (size_t)(cg * CPG) * (H * W);

    float acc[5][9];
#pragma unroll
    for (int j = 0; j < 5; ++j)
#pragma unroll
        for (int p = 0; p < 9; ++p) acc[j][p] = 0.f;

#pragma unroll 6
    for (int cc = 0; cc < CPG; ++cc) {
        const float* f1c = f1w + (size_t)cc * (H * W);
        const float* f2c = f2w + (size_t)cc * (H * W);

        const f4   q0 = *(const f4*)(f2c + o0);
        const f4   q1 = *(const f4*)(f2c + x0);      // e4..e7, always valid
        const f4   q2 = *(const f4*)(f2c + o2);
        const float s3 = f2c[o3];
        const f4   af = *(const f4*)(f1c + x0);      // a0..a3, always valid
        const float a4 = f1c[x0 + 4];                // x0+4 <= 319

        float w_[13];
        w_[0]  = __uint_as_float(__float_as_uint(q0.x) & mlo);
        w_[1]  = __uint_as_float(__float_as_uint(q0.y) & mlo);
        w_[2]  = __uint_as_float(__float_as_uint(q0.z) & mlo);
        w_[3]  = __uint_as_float(__float_as_uint(q0.w) & mlo);
        w_[4]  = q1.x;  w_[5] = q1.y;  w_[6] = q1.z;  w_[7] = q1.w;
        w_[8]  = hi ? q2.w : q2.x;   // lane63's q2 clamped to 316 -> col319=.w
        w_[9]  = __uint_as_float(__float_as_uint(q2.y) & mhi);
        w_[10] = __uint_as_float(__float_as_uint(q2.z) & mhi);
        w_[11] = __uint_as_float(__float_as_uint(q2.w) & mhi);
        w_[12] = __uint_as_float(__float_as_uint(s3)   & mhi);

        const float a_[5] = { af.x, af.y, af.z, af.w, a4 };

        // plane p <-> shift i = p-4; window index e = j + 8 - p
#pragma unroll
        for (int j = 0; j < 5; ++j)
#pragma unroll
            for (int p = 0; p < 9; ++p)
                acc[j][p] = fmaf(a_[j], w_[j + 8 - p], acc[j][p]);
    }

    // partial pre-scaled by 1/FS (mean is linear in channel-group sums)
    const float scale = 1.0f / (float)FS;
    float* wsb = ws + (size_t)cg * CHUNK;
#pragma unroll
    for (int p = 0; p < 9; ++p) {
        float* op = wsb + (((size_t)(b * NPLANES + p)) * H + y) * W + x0;
        f4 v;
        v.x = acc[0][p] * scale;
        v.y = acc[1][p] * scale;
        v.z = acc[2][p] * scale;
        v.w = acc[3][p] * scale;
        *(f4*)op = v;
        op[4] = acc[4][p] * scale;
    }
}

// ---------------- kernel B: sum 4 partials -> out ----------------
// CHUNK/4 quads = 552,960 = 2160 blocks x 256 threads exactly.
__global__ __launch_bounds__(256)
void cost_volume_reduce(const float* __restrict__ ws, float* __restrict__ out)
{
    const size_t i4 = ((size_t)blockIdx.x * 256 + threadIdx.x) * 4;
    f4a a = *(const f4a*)(ws + i4);
    a += *(const f4a*)(ws + (size_t)1 * CHUNK + i4);
    a += *(const f4a*)(ws + (size_t)2 * CHUNK + i4);
    a += *(const f4a*)(ws + (size_t)3 * CHUNK + i4);
    *(f4a*)(out + i4) = a;
}

// ---------------- fallback: verified round-10 fused kernel ----------------
#define RSTRIDE 45
__global__ __launch_bounds__(512)
void cost_volume_fused(const float* __restrict__ f1,
                       const float* __restrict__ f2,
                       float* __restrict__ out)
{
    __shared__ float red[4 * 64 * RSTRIDE];
    const int t   = threadIdx.x;
    const int wv  = t >> 6;
    const int l   = t & 63;
    const int row = blockIdx.x;
    const int b   = row / H;
    const int y   = row % H;
    const int x0 = 5 * l;
    const int o0 = (x0 - 4 < 0)   ? 0   : x0 - 4;
    const int o2 = (x0 + 4 > 316) ? 316 : x0 + 4;
    const int o3 = (x0 + 8 > 319) ? 319 : x0 + 8;
    const unsigned mlo = (l == 0)  ? 0u : ~0u;
    const unsigned mhi = (l == 63) ? 0u : ~0u;
    const bool hi = (l == 63);
    const size_t rowoff = ((size_t)(b * FS) * H + y) * W;
    const float* f1w = f1 + rowoff + (size_t)(wv * 12) * (H * W);
    const float* f2w = f2 + rowoff + (size_t)(wv * 12) * (H * W);
    float acc[5][9];
#pragma unroll
    for (int j = 0; j < 5; ++j)
#pragma unroll
        for (int p = 0; p < 9; ++p) acc[j][p] = 0.f;
#pragma unroll 4
    for (int cc = 0; cc < 12; ++cc) {
        const float* f1c = f1w + (size_t)cc * (H * W);
        const float* f2c = f2w + (size_t)cc * (H * W);
        const f4   q0 = *(const f4*)(f2c + o0);
        const f4   q1 = *(const f4*)(f2c + x0);
        const f4   q2 = *(const f4*)(f2c + o2);
        const float s3 = f2c[o3];
        const f4   af = *(const f4*)(f1c + x0);
        const float a4 = f1c[x0 + 4];
        float w_[13];
        w_[0]  = __uint_as_float(__float_as_uint(q0.x) & mlo);
        w_[1]  = __uint_as_float(__float_as_uint(q0.y) & mlo);
        w_[2]  = __uint_as_float(__float_as_uint(q0.z) & mlo);
        w_[3]  = __uint_as_float(__float_as_uint(q0.w) & mlo);
        w_[4]  = q1.x;  w_[5] = q1.y;  w_[6] = q1.z;  w_[7] = q1.w;
        w_[8]  = hi ? q2.w : q2.x;
        w_[9]  = __uint_as_float(__float_as_uint(q2.y) & mhi);
        w_[10] = __uint_as_float(__float_as_uint(q2.z) & mhi);
        w_[11] = __uint_as_float(__float_as_uint(q2.w) & mhi);
        w_[12] = __uint_as_float(__float_as_uint(s3)   & mhi);
        const float a_[5] = { af.x, af.y, af.z, af.w, a4 };
#pragma unroll
        for (int j = 0; j < 5; ++j)
#pragma unroll
            for (int p = 0; p < 9; ++p)
                acc[j][p] = fmaf(a_[j], w_[j + 8 - p], acc[j][p]);
    }
#define PARK(slot_) do {                                                     \
    float* dst_ = &red[((slot_) * 64 + l) * RSTRIDE];                        \
    _Pragma("unroll")                                                        \
    for (int j = 0; j < 5; ++j)                                              \
        _Pragma("unroll")                                                    \
        for (int p = 0; p < 9; ++p) dst_[j * 9 + p] = acc[j][p];             \
} while (0)
#define GRAB(slot_) do {                                                     \
    const float* src_ = &red[((slot_) * 64 + l) * RSTRIDE];                  \
    _Pragma("unroll")                                                        \
    for (int j = 0; j < 5; ++j)                                              \
        _Pragma("unroll")                                                    \
        for (int p = 0; p < 9; ++p) acc[j][p] += src_[j * 9 + p];            \
} while (0)
    if (wv >= 4) PARK(wv - 4);
    __syncthreads();
    if (wv < 4) GRAB(wv);
    __syncthreads();
    if (wv == 2 || wv == 3) PARK(wv);
    __syncthreads();
    if (wv < 2) GRAB(wv + 2);
    __syncthreads();
    if (wv == 1) PARK(0);
    __syncthreads();
    if (wv == 0) {
        GRAB(0);
        const float scale = 1.0f / (float)FS;
#pragma unroll
        for (int p = 0; p < 9; ++p) {
            float* op = out + (((size_t)(b * NPLANES + p)) * H + y) * W + x0;
            f4 v;
            v.x = acc[0][p] * scale;
            v.y = acc[1][p] * scale;
            v.z = acc[2][p] * scale;
            v.w = acc[3][p] * scale;
            *(f4*)op = v;
            op[4] = acc[4][p] * scale;
        }
    }
#undef PARK
#undef GRAB
}

extern "C" void kernel_launch(void* const* d_in, const int* in_sizes, int n_in,
                              void* d_out, int out_size, void* d_ws, size_t ws_size,
                              hipStream_t stream) {
    (void)in_sizes; (void)n_in; (void)out_size;
    const float* f1 = (const float*)d_in[0];
    const float* f2 = (const float*)d_in[1];
    float* out = (float*)d_out;

    const size_t ws_need = (size_t)NCG * CHUNK * sizeof(float);   // 35.4 MB
    if (d_ws != nullptr && ws_size >= ws_need) {
        float* ws = (float*)d_ws;
        cost_volume_partial<<<dim3(BS * 24 * NCG), dim3(NTHREADS), 0, stream>>>(f1, f2, ws);
        cost_volume_reduce<<<dim3(CHUNK / 4 / 256), dim3(256), 0, stream>>>(ws, out);
    } else {
        cost_volume_fused<<<dim3(BS * H), dim3(512), 0, stream>>>(f1, f2, out);
    }
}

// Round 13
// 206.441 us; speedup vs baseline: 1.1305x; 1.1305x over previous
//
#include <hip/hip_runtime.h>

#define W 320
#define H 96
#define FS 96
#define BS 8
#define NPLANES 9
#define CPW 12            // channels per wave (FS / 8 waves)
#define NTHREADS 512      // 8 waves per block, one (b,y) row per block
#define HW (H * W)
#define RSTRIDE 45        // reduction lane-slot stride (odd -> 2-way = free)

// 4-byte-aligned float4 (x0 = 5*lane is only dword-aligned)
typedef float f4 __attribute__((ext_vector_type(4), aligned(4)));

typedef const __attribute__((address_space(1))) void* gp1_t;
typedef __attribute__((address_space(3))) void*       lp3_t;

// async global->LDS DMA, 16 B per lane. Dest is WAVE-UNIFORM base; lane i
// lands at base + 16*i (m104). Src is per-lane. Counted by vmcnt.
__device__ __forceinline__ void glds16(const float* g, float* l_) {
    __builtin_amdgcn_global_load_lds((gp1_t)g, (lp3_t)l_, 16, 0, 0);
}

__global__ __launch_bounds__(NTHREADS)   // NO min-waves clamp (R8 lesson)
void cost_volume_kernel(const float* __restrict__ f1,
                        const float* __restrict__ f2,
                        float* __restrict__ out)
{
    // one pool, two phases:
    //  phase 1 (channel loop): per-wave private staging, wv*1280 + buf*640
    //    floats; [0..320)=f2 row, [320..640)=f1 row. 8 waves * 1280 = 10240.
    //  phase 2 (after barrier): reduction slots 4*64*RSTRIDE = 11520 floats.
    __shared__ float pool[4 * 64 * RSTRIDE];   // 46,080 B -> 3 blocks/CU

    const int t   = threadIdx.x;
    const int wv  = t >> 6;          // wave 0..7
    const int l   = t & 63;          // lane
    const int row = blockIdx.x;      // 0..767 = (b, y)
    const int b   = row / H;
    const int y   = row % H;

    const int x0 = 5 * l;            // output cols x0..x0+4 (64*5 = 320)
    const unsigned mlo = (l == 0)  ? 0u : ~0u;   // cols <0 only at lane 0
    const unsigned mhi = (l == 63) ? 0u : ~0u;   // cols >319 only at lane 63

    const size_t rowoff = ((size_t)(b * FS) * H + y) * W;
    const float* f1w = f1 + rowoff + (size_t)(wv * CPW) * HW;
    const float* f2w = f2 + rowoff + (size_t)(wv * CPW) * HW;

    float* const bufA = &pool[wv * 1280];
    float* const bufB = bufA + 640;

    float acc[5][9];
#pragma unroll
    for (int j = 0; j < 5; ++j)
#pragma unroll
        for (int p = 0; p < 9; ++p) acc[j][p] = 0.f;

// ---- stage channel cc_ into D_ : 4 DMA issues (f2 row, f1 row) ----
#define STAGE(cc_, D_) do {                                                  \
    const float* f2c_ = f2w + (size_t)(cc_) * HW;                            \
    const float* f1c_ = f1w + (size_t)(cc_) * HW;                            \
    glds16(f2c_ + 4 * l, D_);              /* f2 cols 0..255   */            \
    glds16(f1c_ + 4 * l, D_ + 320);        /* f1 cols 0..255   */            \
    if (l < 16) {                                                            \
        glds16(f2c_ + 256 + 4 * l, D_ + 256);        /* f2 256..319 */       \
        glds16(f1c_ + 256 + 4 * l, D_ + 320 + 256);  /* f1 256..319 */       \
    }                                                                        \
} while (0)

// ---- compute channel from staged rows in D_ ----
// wv_[e] = f2[x0-4+e] (zero-padded), e=0..12; middle e=4..8 always in range.
// Edge lanes read a clamped index and AND-mask the value (not mul: masked
// slots may alias arbitrary data).
#define COMP(D_) do {                                                        \
    const float* s2_ = D_;                                                   \
    const float* s1_ = D_ + 320;                                             \
    float wv_[13];                                                           \
    _Pragma("unroll")                                                        \
    for (int e = 0; e < 4; ++e) {                                            \
        const int col = x0 - 4 + e;                                          \
        const int cl  = col < 0 ? 0 : col;                                   \
        wv_[e] = __uint_as_float(__float_as_uint(s2_[cl]) & mlo);            \
    }                                                                        \
    _Pragma("unroll")                                                        \
    for (int e = 4; e < 9; ++e) wv_[e] = s2_[x0 - 4 + e];                    \
    _Pragma("unroll")                                                        \
    for (int e = 9; e < 13; ++e) {                                           \
        const int col = x0 - 4 + e;                                          \
        const int cl  = col > 319 ? 319 : col;                               \
        wv_[e] = __uint_as_float(__float_as_uint(s2_[cl]) & mhi);            \
    }                                                                        \
    float a_[5];                                                             \
    _Pragma("unroll")                                                        \
    for (int j = 0; j < 5; ++j) a_[j] = s1_[x0 + j];                         \
    /* plane p <-> shift i = p-4; window index e = j + 8 - p */              \
    _Pragma("unroll")                                                        \
    for (int j = 0; j < 5; ++j)                                              \
        _Pragma("unroll")                                                    \
        for (int p = 0; p < 9; ++p)                                          \
            acc[j][p] = fmaf(a_[j], wv_[j + 8 - p], acc[j][p]);              \
} while (0)

// wait until only the newest 4 DMA issues remain in flight (i.e. the
// OLDER buffer's 4 have landed). "memory" stops ds_reads crossing it.
#define VW4() asm volatile("s_waitcnt vmcnt(4)" ::: "memory")
#define VW0() asm volatile("s_waitcnt vmcnt(0)" ::: "memory")

    // Per-wave private double-buffered DMA pipeline: NO barriers inside.
    STAGE(0, bufA);
    STAGE(1, bufB);            // 8 issues outstanding
    VW4();  COMP(bufA);  STAGE(2,  bufA);   // ch0
    VW4();  COMP(bufB);  STAGE(3,  bufB);   // ch1
    VW4();  COMP(bufA);  STAGE(4,  bufA);   // ch2
    VW4();  COMP(bufB);  STAGE(5,  bufB);   // ch3
    VW4();  COMP(bufA);  STAGE(6,  bufA);   // ch4
    VW4();  COMP(bufB);  STAGE(7,  bufB);   // ch5
    VW4();  COMP(bufA);  STAGE(8,  bufA);   // ch6
    VW4();  COMP(bufB);  STAGE(9,  bufB);   // ch7
    VW4();  COMP(bufA);  STAGE(10, bufA);   // ch8
    VW4();  COMP(bufB);  STAGE(11, bufB);   // ch9
    VW4();  COMP(bufA);                     // ch10
    VW0();  COMP(bufB);                     // ch11 (all DMA drained)

#undef STAGE
#undef COMP
#undef VW4
#undef VW0

    // ---- phase 2: 3-phase LDS tree reduction (pool reused after barrier) --
    __syncthreads();

#define PARK(slot_) do {                                                     \
    float* dst_ = &pool[((slot_) * 64 + l) * RSTRIDE];                       \
    _Pragma("unroll")                                                        \
    for (int j = 0; j < 5; ++j)                                              \
        _Pragma("unroll")                                                    \
        for (int p = 0; p < 9; ++p) dst_[j * 9 + p] = acc[j][p];             \
} while (0)

#define GRAB(slot_) do {                                                     \
    const float* src_ = &pool[((slot_) * 64 + l) * RSTRIDE];                 \
    _Pragma("unroll")                                                        \
    for (int j = 0; j < 5; ++j)                                              \
        _Pragma("unroll")                                                    \
        for (int p = 0; p < 9; ++p) acc[j][p] += src_[j * 9 + p];            \
} while (0)

    if (wv >= 4) PARK(wv - 4);
    __syncthreads();
    if (wv < 4) GRAB(wv);
    __syncthreads();                 // anti-dep: reads done before re-write
    if (wv == 2 || wv == 3) PARK(wv);
    __syncthreads();
    if (wv < 2) GRAB(wv + 2);
    __syncthreads();
    if (wv == 1) PARK(0);
    __syncthreads();
    if (wv == 0) {
        GRAB(0);
        const float scale = 1.0f / (float)FS;
#pragma unroll
        for (int p = 0; p < 9; ++p) {
            float* op = out + (((size_t)(b * NPLANES + p)) * H + y) * W + x0;
            f4 v;
            v.x = acc[0][p] * scale;
            v.y = acc[1][p] * scale;
            v.z = acc[2][p] * scale;
            v.w = acc[3][p] * scale;
            *(f4*)op = v;
            op[4] = acc[4][p] * scale;
        }
    }

#undef PARK
#undef GRAB
}

extern "C" void kernel_launch(void* const* d_in, const int* in_sizes, int n_in,
                              void* d_out, int out_size, void* d_ws, size_t ws_size,
                              hipStream_t stream) {
    (void)in_sizes; (void)n_in; (void)d_ws; (void)ws_size; (void)out_size;
    const float* f1 = (const float*)d_in[0];
    const float* f2 = (const float*)d_in[1];
    float* out = (float*)d_out;

    dim3 grid(BS * H);        // 768 blocks x 8 waves
    dim3 block(NTHREADS);
    cost_volume_kernel<<<grid, block, 0, stream>>>(f1, f2, out);
}